// Round 13
// baseline (304.899 us; speedup 1.0000x reference)
//
#include <hip/hip_runtime.h>
#include <hip/hip_bf16.h>

#define NB 8192   // batch
#define ND 1024   // feature dim

typedef __bf16 bf16x8 __attribute__((ext_vector_type(8)));
typedef float  f32x4  __attribute__((ext_vector_type(4)));

__device__ inline unsigned short f2bf(float x) {
    unsigned int u = __float_as_uint(x);
    return (unsigned short)((u + 0x7fffu + ((u >> 16) & 1u)) >> 16);
}

__device__ inline float bf2f(unsigned short u) {
    unsigned int v = ((unsigned int)u) << 16;
    return __uint_as_float(v);
}

// ---------------------------------------------------------------------------
// Kernel 1: per-row L2 norms of A and B + bf16 conversion into MFMA-fragment-
// packed layout: idx(row, k) = (row>>4)*16384 + (k>>3)*128 + (row&15)*8 + (k&7)
// so a wave's fragment load (16 rows x 8 k) is one coalesced dwordx4/lane.
// ---------------------------------------------------------------------------
__global__ __launch_bounds__(256) void prep_kernel(
    const float* __restrict__ A, const float* __restrict__ Bm,
    unsigned short* __restrict__ wa2, unsigned short* __restrict__ wb2,
    float* __restrict__ na, float* __restrict__ nb)
{
    int b = blockIdx.x;
    int wid = threadIdx.x >> 6, lane = threadIdx.x & 63;
    bool isA = (b < 2048);
    int row = (isA ? b : b - 2048) * 4 + wid;
    const float*    rp  = (isA ? A : Bm) + (size_t)row * ND;
    unsigned short* dst = (isA ? wa2 : wb2);

    const size_t rbase = (size_t)(row >> 4) * 16384 + (row & 15) * 8;

    float ss = 0.f;
#pragma unroll
    for (int t = 0; t < 4; ++t) {
        int c = lane * 4 + t * 256;
        float4 v = *reinterpret_cast<const float4*>(rp + c);
        ss += v.x * v.x + v.y * v.y + v.z * v.z + v.w * v.w;
        ushort4 u;
        u.x = f2bf(v.x); u.y = f2bf(v.y); u.z = f2bf(v.z); u.w = f2bf(v.w);
        size_t idx = rbase + (size_t)(c >> 3) * 128 + (c & 7);
        *reinterpret_cast<ushort4*>(dst + idx) = u;
    }
#pragma unroll
    for (int off = 32; off; off >>= 1) ss += __shfl_xor(ss, off);
    if (lane == 0) (isA ? na : nb)[row] = sqrtf(ss);
}

// ---------------------------------------------------------------------------
// Kernel 2: label histogram (integer LDS atomics -> deterministic).
// ---------------------------------------------------------------------------
__global__ __launch_bounds__(256) void hist_kernel(
    const int* __restrict__ labels, int* __restrict__ hist)
{
    __shared__ int h[128];
    int tid = threadIdx.x;
    if (tid < 128) h[tid] = 0;
    __syncthreads();
    for (int i = tid; i < NB; i += 256) atomicAdd(&h[labels[i]], 1);
    __syncthreads();
    if (tid < 128) hist[tid] = h[tid];
}

// ---------------------------------------------------------------------------
// Kernel 3: barrier-free, LDS-free 64x64-tile bf16 GEMM. ONE wave per block;
// A and B fragments loaded directly from fragment-packed global (coalesced
// dwordx4), register double-buffered; compiler inserts exact counted vmcnt.
// No __shared__, no s_barrier, no DMA -> zero sync stalls; latency hidden by
// 12 independent waves/CU (m114 TLP). XCD map: each XCD owns 16 tm rows
// (A panel 2MB L2-resident); tn-major order so 16 consecutive blocks reuse
// each B panel from L2.
// Epilogue: scale to cos, write C, per-row loss partials (shfl-reduced,
// bf16-stored) -- single wave, no sync needed.
// ---------------------------------------------------------------------------
__global__ __launch_bounds__(64, 3) void gemm_cos(
    const unsigned short* __restrict__ wa2, const unsigned short* __restrict__ wb2,
    const float* __restrict__ na, const float* __restrict__ nb,
    const int* __restrict__ labels,
    float* __restrict__ C,
    unsigned short* __restrict__ pe, unsigned short* __restrict__ pm)
{
    const int bid = blockIdx.x;                 // 16384 blocks
    const int tm  = (bid & 7) * 16 + ((bid >> 3) & 15);  // XCD owns 16 tm rows
    const int tn  = bid >> 7;                             // 0..127, B reused 16x

    const int lane = threadIdx.x & 63;
    const int l15  = lane & 15, lg = lane >> 4;

    const int m0 = tm * 64, n0 = tn * 64;

    // Fragment base pointers: chunk (16 rows x 1024 k) stride 16384 shorts.
    const unsigned short* pa[4];
    const unsigned short* pb[4];
#pragma unroll
    for (int m = 0; m < 4; ++m) {
        pa[m] = wa2 + (size_t)(tm * 4 + m) * 16384 + lg * 128 + l15 * 8;
        pb[m] = wb2 + (size_t)(tn * 4 + m) * 16384 + lg * 128 + l15 * 8;
    }

    f32x4 acc[4][4];
#pragma unroll
    for (int i = 0; i < 4; ++i)
#pragma unroll
        for (int j = 0; j < 4; ++j) acc[i][j] = (f32x4){0.f, 0.f, 0.f, 0.f};

    bf16x8 a[2][4], b[2][4];
#pragma unroll
    for (int m = 0; m < 4; ++m) {
        a[0][m] = *reinterpret_cast<const bf16x8*>(pa[m]);
        b[0][m] = *reinterpret_cast<const bf16x8*>(pb[m]);
    }

#pragma unroll
    for (int t = 0; t < 32; ++t) {
        const int cur = t & 1, nxt = cur ^ 1;
        if (t < 31) {
#pragma unroll
            for (int m = 0; m < 4; ++m) {
                a[nxt][m] = *reinterpret_cast<const bf16x8*>(pa[m] + (t + 1) * 512);
                b[nxt][m] = *reinterpret_cast<const bf16x8*>(pb[m] + (t + 1) * 512);
            }
        }
#pragma unroll
        for (int m = 0; m < 4; ++m)
#pragma unroll
            for (int n = 0; n < 4; ++n)
                acc[m][n] = __builtin_amdgcn_mfma_f32_16x16x32_bf16(
                    a[cur][m], b[cur][n], acc[m][n], 0, 0, 0);
    }

    // ---------------- epilogue: cos write + loss partials (no sync) --------
    float nbv[4]; int labc[4];
#pragma unroll
    for (int n = 0; n < 4; ++n) {
        int c = n0 + n * 16 + l15;
        nbv[n] = nb[c]; labc[n] = labels[c];
    }

#pragma unroll
    for (int m = 0; m < 4; ++m) {
#pragma unroll
        for (int jj = 0; jj < 4; ++jj) {
            int r = m0 + m * 16 + lg * 4 + jj;
            float nav = na[r]; int labr = labels[r];
            float es = 0.f, ms = 0.f;
#pragma unroll
            for (int n = 0; n < 4; ++n) {
                int c = n0 + n * 16 + l15;
                float v = acc[m][n][jj] / fmaxf(nav * nbv[n], 1e-8f);
                C[(size_t)r * NB + c] = v;
                es += __expf(v);
                ms += (labc[n] == labr) ? v : 0.f;
            }
#pragma unroll
            for (int off = 1; off < 16; off <<= 1) {
                es += __shfl_xor(es, off);
                ms += __shfl_xor(ms, off);
            }
            if (l15 == 0) {
                pe[tn * NB + r] = f2bf(es);
                pm[tn * NB + r] = f2bf(ms);
            }
        }
    }
}

// ---------------------------------------------------------------------------
// Kernel 4: reduce 128 column-tile partials (bf16) -> per-row loss.
// ---------------------------------------------------------------------------
__global__ __launch_bounds__(256) void loss_final(
    const unsigned short* __restrict__ pe, const unsigned short* __restrict__ pm,
    const int* __restrict__ labels, const int* __restrict__ hist,
    float* __restrict__ per_row)
{
    int row = blockIdx.x * 256 + threadIdx.x;
    float es = 0.f, ms = 0.f;
#pragma unroll
    for (int t = 0; t < 128; ++t) {
        es += bf2f(pe[t * NB + row]);
        ms += bf2f(pm[t * NB + row]);
    }
    per_row[row] = logf(es) - ms / (float)hist[labels[row]];
}

// ---------------------------------------------------------------------------
// Kernel 5: deterministic mean of per_row -> out[0]
// ---------------------------------------------------------------------------
__global__ __launch_bounds__(256) void finalize(
    const float* __restrict__ per_row, float* __restrict__ out)
{
    __shared__ float sm[256];
    float s = 0.f;
    for (int i = threadIdx.x; i < NB; i += 256) s += per_row[i];
    sm[threadIdx.x] = s;
    __syncthreads();
    for (int k = 128; k; k >>= 1) {
        if (threadIdx.x < k) sm[threadIdx.x] += sm[threadIdx.x + k];
        __syncthreads();
    }
    if (threadIdx.x == 0) out[0] = sm[0] * (1.0f / (float)NB);
}

extern "C" void kernel_launch(void* const* d_in, const int* in_sizes, int n_in,
                              void* d_out, int out_size, void* d_ws, size_t ws_size,
                              hipStream_t stream) {
    const int*   labels = (const int*)d_in[0];
    const float* A      = (const float*)d_in[1];
    const float* Bm     = (const float*)d_in[2];
    float* out = (float*)d_out;

    // workspace layout (37.9 MB -- same footprint as proven rounds)
    char* ws = (char*)d_ws;
    unsigned short* wa2 = (unsigned short*)(ws);                    // 16 MB
    unsigned short* wb2 = (unsigned short*)(ws + 16777216);         // 16 MB
    float* na      = (float*)(ws + 33554432);                       // 32 KB
    float* nb      = (float*)(ws + 33554432 + 32768);               // 32 KB
    float* per_row = (float*)(ws + 33554432 + 65536);               // 32 KB
    int*   hist    = (int*)  (ws + 33554432 + 98304);               // 512 B
    unsigned short* pe = (unsigned short*)(ws + 33554432 + 131072);           // 2 MB
    unsigned short* pm = (unsigned short*)(ws + 33554432 + 131072 + 2097152); // 2 MB

    float* cosm = out + 1;   // out[0]=loss, out[1..] = cos_score row-major

    prep_kernel<<<4096,  256, 0, stream>>>(A, Bm, wa2, wb2, na, nb);
    hist_kernel<<<1,     256, 0, stream>>>(labels, hist);
    gemm_cos   <<<16384,  64, 0, stream>>>(wa2, wb2, na, nb, labels, cosm, pe, pm);
    loss_final <<<32,    256, 0, stream>>>(pe, pm, labels, hist, per_row);
    finalize   <<<1,     256, 0, stream>>>(per_row, out);
}

// Round 14
// 285.354 us; speedup vs baseline: 1.0685x; 1.0685x over previous
//
#include <hip/hip_runtime.h>
#include <hip/hip_bf16.h>

#define NB 8192   // batch
#define ND 1024   // feature dim

typedef __bf16 bf16x8 __attribute__((ext_vector_type(8)));
typedef float  f32x4  __attribute__((ext_vector_type(4)));

// async global -> LDS, 16B per lane. LDS dest = wave-uniform base + lane*16.
__device__ inline void gload_lds16(const void* g, void* l) {
    __builtin_amdgcn_global_load_lds(
        (const __attribute__((address_space(1))) unsigned int*)g,
        (__attribute__((address_space(3))) unsigned int*)l,
        16, 0, 0);
}

__device__ inline unsigned short f2bf(float x) {
    unsigned int u = __float_as_uint(x);
    return (unsigned short)((u + 0x7fffu + ((u >> 16) & 1u)) >> 16);
}

#define BARRIER() asm volatile("s_barrier" ::: "memory")
#define VMCNT2()  asm volatile("s_waitcnt vmcnt(2)" ::: "memory")
#define VMCNT0()  asm volatile("s_waitcnt vmcnt(0)" ::: "memory")
#define LGKM0()   asm volatile("s_waitcnt lgkmcnt(0)" ::: "memory")

// ---------------------------------------------------------------------------
// Kernel 1: per-row L2 norms of A and B + bf16 conversion into workspace.
// ---------------------------------------------------------------------------
__global__ __launch_bounds__(256) void prep_kernel(
    const float* __restrict__ A, const float* __restrict__ Bm,
    unsigned short* __restrict__ wa, unsigned short* __restrict__ wb,
    float* __restrict__ na, float* __restrict__ nb)
{
    int b = blockIdx.x;
    int wid = threadIdx.x >> 6, lane = threadIdx.x & 63;
    const float* src; unsigned short* dst; float* nrm; int row;
    if (b < 2048) { src = A;  dst = wa; nrm = na; row = b * 4 + wid; }
    else          { src = Bm; dst = wb; nrm = nb; row = (b - 2048) * 4 + wid; }

    const float*    rp = src + (size_t)row * ND;
    unsigned short* wp = dst + (size_t)row * ND;

    float ss = 0.f;
#pragma unroll
    for (int t = 0; t < 4; ++t) {
        int c = lane * 4 + t * 256;
        float4 v = *reinterpret_cast<const float4*>(rp + c);
        ss += v.x * v.x + v.y * v.y + v.z * v.z + v.w * v.w;
        ushort4 u;
        u.x = f2bf(v.x); u.y = f2bf(v.y); u.z = f2bf(v.z); u.w = f2bf(v.w);
        *reinterpret_cast<ushort4*>(wp + c) = u;
    }
#pragma unroll
    for (int off = 32; off; off >>= 1) ss += __shfl_xor(ss, off);
    if (lane == 0) nrm[row] = sqrtf(ss);
}

// ---------------------------------------------------------------------------
// Kernel 2: label histogram (integer LDS atomics -> deterministic).
// ---------------------------------------------------------------------------
__global__ __launch_bounds__(256) void hist_kernel(
    const int* __restrict__ labels, int* __restrict__ hist)
{
    __shared__ int h[128];
    int tid = threadIdx.x;
    if (tid < 128) h[tid] = 0;
    __syncthreads();
    for (int i = tid; i < NB; i += 256) atomicAdd(&h[labels[i]], 1);
    __syncthreads();
    if (tid < 128) hist[tid] = h[tid];
}

// ---------------------------------------------------------------------------
// Kernel 3: 128x128-tile bf16 GEMM, BK=32. LDS 40 KiB -> 4 blocks/CU
// (16 waves, __launch_bounds__(256,4), VGPR<=128): A tri-buffered (3x8 KiB,
// staged 2 ahead), B double-buffered (2x8 KiB, staged 1 ahead).
// Loop invariant: outstanding VMEM at each barrier = {A(t+2)} (2 loads).
//   iter t: issue B(t+1), then A(t+2); COMPUTE(A(t),B(t)); vmcnt(2)
//   [retires A(t+1) (1 iter old) + B(t+1) (covered by 16 MFMA + 8 ds_read)];
//   lgkmcnt(0) [ds_reads drained -> buffer handoff safe]; s_barrier.
// Every wave retires its staging before the barrier preceding consumption ->
// cross-wave visibility guaranteed (R11's bug class excluded). Stage targets
// A((t+2)%3)/B((t+1)&1) were read in iter t-1, drained by its lgkm+barrier.
// Tails: t=30,31 use vmcnt(0). R8-verified swizzle (0 conflicts), XCD map.
// Epilogue: scale to cos, write C, fused per-row loss partials.
// ---------------------------------------------------------------------------
__global__ __launch_bounds__(256, 4) void gemm_cos(
    const unsigned short* __restrict__ wa, const unsigned short* __restrict__ wb,
    const float* __restrict__ na, const float* __restrict__ nb,
    const int* __restrict__ labels,
    float* __restrict__ C, float* __restrict__ pe, float* __restrict__ pm)
{
    // A bufs @ 0,4096,8192 ; B bufs @ 12288,16384 (shorts) = 40 KiB
    __shared__ unsigned short lds[20480];

    const int bid = blockIdx.x;                 // 4096 blocks
    const int tm  = (bid & 7) * 8 + ((bid >> 3) & 7);   // XCD owns 8 tm rows
    const int tn  = bid >> 6;                            // B streams

    const int tid  = threadIdx.x;
    const int lane = tid & 63;
    const int wid  = tid >> 6;
    const int wr   = wid >> 1, wc = wid & 1;
    const int l15  = lane & 15, lg = lane >> 4;

    const int m0 = tm * 128, n0 = tn * 128;

    // Staging: thread -> row tid>>2 (0..63 per gload), granule tid&3; global
    // granule pre-swizzled: (tid&3) ^ ((row>>1)&3).
    const int srow = tid >> 2;
    const int sg   = (tid & 3) ^ ((tid >> 3) & 3);
    const unsigned short* pA0 = wa + (size_t)(m0 + srow) * ND + sg * 8;
    const unsigned short* pA1 = pA0 + 64 * ND;
    const unsigned short* pB0 = wb + (size_t)(n0 + srow) * ND + sg * 8;
    const unsigned short* pB1 = pB0 + 64 * ND;
    const int stW = wid * 512;   // wave-uniform LDS dest base per 64-row call

    // Fragment reads: kg = (lg ^ ((row>>1)&3))*8; row bits from l15 only.
    const int kg  = (lg ^ ((lane >> 1) & 3)) * 8;
    const int rdA = wr * 2048 + l15 * 32 + kg;            // + m*512 (+ A buf)
    const int rdB = wc * 2048 + l15 * 32 + kg;            // + n*512 (+ B buf)

    f32x4 acc[4][4];
#pragma unroll
    for (int i = 0; i < 4; ++i)
#pragma unroll
        for (int j = 0; j < 4; ++j) acc[i][j] = (f32x4){0.f, 0.f, 0.f, 0.f};

#define STAGE_A(t, BUF) do { \
    gload_lds16(pA0 + (t) * 32, &lds[(BUF) + stW]); \
    gload_lds16(pA1 + (t) * 32, &lds[(BUF) + 2048 + stW]); } while (0)

#define STAGE_B(t, BUF) do { \
    gload_lds16(pB0 + (t) * 32, &lds[(BUF) + stW]); \
    gload_lds16(pB1 + (t) * 32, &lds[(BUF) + 2048 + stW]); } while (0)

#define COMPUTE(ABUF, BBUF) do { \
    bf16x8 bq[4], af[4]; \
    _Pragma("unroll") \
    for (int n_ = 0; n_ < 4; ++n_) \
        bq[n_] = *reinterpret_cast<const bf16x8*>(&lds[(BBUF) + rdB + n_ * 512]); \
    _Pragma("unroll") \
    for (int m_ = 0; m_ < 4; ++m_) \
        af[m_] = *reinterpret_cast<const bf16x8*>(&lds[(ABUF) + rdA + m_ * 512]); \
    _Pragma("unroll") \
    for (int m_ = 0; m_ < 4; ++m_) \
        _Pragma("unroll") \
        for (int n_ = 0; n_ < 4; ++n_) \
            acc[m_][n_] = __builtin_amdgcn_mfma_f32_16x16x32_bf16( \
                af[m_], bq[n_], acc[m_][n_], 0, 0, 0); \
    } while (0)

    // Prologue (order matters for vmcnt counting): A(0), B(0), A(1).
    STAGE_A(0, 0);
    STAGE_B(0, 12288);
    STAGE_A(1, 4096);
    VMCNT2();            // A(0), B(0) landed; A(1) still in flight
    BARRIER();

#pragma unroll
    for (int t = 0; t < 32; ++t) {
        const int ab = (t % 3) * 4096;                  // A consume buf
        const int bb = 12288 + (t & 1) * 4096;          // B consume buf
        // issue-early: B(t+1) first, then A(t+2) (newest 2 = A(t+2))
        if (t < 31) STAGE_B(t + 1, 12288 + ((t + 1) & 1) * 4096);
        if (t < 30) STAGE_A(t + 2, ((t + 2) % 3) * 4096);
        COMPUTE(ab, bb);                                // ~500 cyc of cover
        if (t < 30) VMCNT2();      // retire A(t+1) + B(t+1); leave A(t+2)
        else        VMCNT0();      // tails: drain everything
        LGKM0();                   // ds_reads drained: buffer handoff safe
        BARRIER();
    }

#undef COMPUTE
#undef STAGE_B
#undef STAGE_A

    // ---------------- epilogue: cos write + fused loss partials ------------
    __syncthreads();                 // LDS reusable
    float* pl = reinterpret_cast<float*>(lds);   // [128 rows][2 wc][2] floats

    float nbv[4]; int labc[4];
#pragma unroll
    for (int n = 0; n < 4; ++n) {
        int c = n0 + wc * 64 + n * 16 + l15;
        nbv[n] = nb[c]; labc[n] = labels[c];
    }

#pragma unroll
    for (int m = 0; m < 4; ++m) {
#pragma unroll
        for (int jj = 0; jj < 4; ++jj) {
            int rl = wr * 64 + m * 16 + lg * 4 + jj;   // 0..127
            int r  = m0 + rl;
            float nav = na[r]; int labr = labels[r];
            float es = 0.f, ms = 0.f;
#pragma unroll
            for (int n = 0; n < 4; ++n) {
                int c = n0 + wc * 64 + n * 16 + l15;
                float v = acc[m][n][jj] / fmaxf(nav * nbv[n], 1e-8f);
                C[(size_t)r * NB + c] = v;
                es += __expf(v);
                ms += (labc[n] == labr) ? v : 0.f;
            }
#pragma unroll
            for (int off = 1; off < 16; off <<= 1) {
                es += __shfl_xor(es, off);
                ms += __shfl_xor(ms, off);
            }
            if (l15 == 0) {
                int o = rl * 4 + wc * 2;
                pl[o] = es; pl[o + 1] = ms;
            }
        }
    }
    __syncthreads();
    if (tid < 128) {
        float es = pl[tid * 4]     + pl[tid * 4 + 2];
        float ms = pl[tid * 4 + 1] + pl[tid * 4 + 3];
        pe[tn * NB + m0 + tid] = es;
        pm[tn * NB + m0 + tid] = ms;
    }
}

// ---------------------------------------------------------------------------
// Kernel 4: reduce 64 column-tile partials -> per-row loss.
// ---------------------------------------------------------------------------
__global__ __launch_bounds__(256) void loss_final(
    const float* __restrict__ pe, const float* __restrict__ pm,
    const int* __restrict__ labels, const int* __restrict__ hist,
    float* __restrict__ per_row)
{
    int row = blockIdx.x * 256 + threadIdx.x;
    float es = 0.f, ms = 0.f;
#pragma unroll
    for (int t = 0; t < 64; ++t) {
        es += pe[t * NB + row];
        ms += pm[t * NB + row];
    }
    per_row[row] = logf(es) - ms / (float)hist[labels[row]];
}

// ---------------------------------------------------------------------------
// Kernel 5: deterministic mean of per_row -> out[0]
// ---------------------------------------------------------------------------
__global__ __launch_bounds__(256) void finalize(
    const float* __restrict__ per_row, float* __restrict__ out)
{
    __shared__ float sm[256];
    float s = 0.f;
    for (int i = threadIdx.x; i < NB; i += 256) s += per_row[i];
    sm[threadIdx.x] = s;
    __syncthreads();
    for (int k = 128; k; k >>= 1) {
        if (threadIdx.x < k) sm[threadIdx.x] += sm[threadIdx.x + k];
        __syncthreads();
    }
    if (threadIdx.x == 0) out[0] = sm[0] * (1.0f / (float)NB);
}

extern "C" void kernel_launch(void* const* d_in, const int* in_sizes, int n_in,
                              void* d_out, int out_size, void* d_ws, size_t ws_size,
                              hipStream_t stream) {
    const int*   labels = (const int*)d_in[0];
    const float* A      = (const float*)d_in[1];
    const float* Bm     = (const float*)d_in[2];
    float* out = (float*)d_out;

    // workspace layout (~38.2 MB)
    char* ws = (char*)d_ws;
    unsigned short* wa = (unsigned short*)(ws);                     // 16 MB
    unsigned short* wb = (unsigned short*)(ws + 16777216);          // 16 MB
    float* na      = (float*)(ws + 33554432);                       // 32 KB
    float* nb      = (float*)(ws + 33554432 + 32768);               // 32 KB
    float* per_row = (float*)(ws + 33554432 + 65536);               // 32 KB
    int*   hist    = (int*)  (ws + 33554432 + 98304);               // 512 B
    float* pe      = (float*)(ws + 33554432 + 131072);              // 2 MB
    float* pm      = (float*)(ws + 33554432 + 131072 + 2097152);    // 2 MB

    float* cosm = out + 1;   // out[0]=loss, out[1..] = cos_score row-major

    prep_kernel<<<4096, 256, 0, stream>>>(A, Bm, wa, wb, na, nb);
    hist_kernel<<<1,    256, 0, stream>>>(labels, hist);
    gemm_cos   <<<4096, 256, 0, stream>>>(wa, wb, na, nb, labels, cosm, pe, pm);
    loss_final <<<32,   256, 0, stream>>>(pe, pm, labels, hist, per_row);
    finalize   <<<1,    256, 0, stream>>>(per_row, out);
}

// Round 15
// 270.271 us; speedup vs baseline: 1.1281x; 1.0558x over previous
//
#include <hip/hip_runtime.h>
#include <hip/hip_bf16.h>

#define NB 8192   // batch
#define ND 1024   // feature dim

typedef __bf16 bf16x8 __attribute__((ext_vector_type(8)));
typedef float  f32x4  __attribute__((ext_vector_type(4)));

// async global -> LDS, 16B per lane. LDS dest = wave-uniform base + lane*16.
__device__ inline void gload_lds16(const void* g, void* l) {
    __builtin_amdgcn_global_load_lds(
        (const __attribute__((address_space(1))) unsigned int*)g,
        (__attribute__((address_space(3))) unsigned int*)l,
        16, 0, 0);
}

__device__ inline unsigned short f2bf(float x) {
    unsigned int u = __float_as_uint(x);
    return (unsigned short)((u + 0x7fffu + ((u >> 16) & 1u)) >> 16);
}

#define BARRIER() asm volatile("s_barrier" ::: "memory")
#define VMCNT6()  asm volatile("s_waitcnt vmcnt(6)" ::: "memory")
#define VMCNT0()  asm volatile("s_waitcnt vmcnt(0)" ::: "memory")
#define LGKM0()   asm volatile("s_waitcnt lgkmcnt(0)" ::: "memory")

// ---------------------------------------------------------------------------
// Kernel 1: per-row L2 norms of A and B + bf16 conversion into workspace.
// ---------------------------------------------------------------------------
__global__ __launch_bounds__(256) void prep_kernel(
    const float* __restrict__ A, const float* __restrict__ Bm,
    unsigned short* __restrict__ wa, unsigned short* __restrict__ wb,
    float* __restrict__ na, float* __restrict__ nb)
{
    int b = blockIdx.x;
    int wid = threadIdx.x >> 6, lane = threadIdx.x & 63;
    const float* src; unsigned short* dst; float* nrm; int row;
    if (b < 2048) { src = A;  dst = wa; nrm = na; row = b * 4 + wid; }
    else          { src = Bm; dst = wb; nrm = nb; row = (b - 2048) * 4 + wid; }

    const float*    rp = src + (size_t)row * ND;
    unsigned short* wp = dst + (size_t)row * ND;

    float ss = 0.f;
#pragma unroll
    for (int t = 0; t < 4; ++t) {
        int c = lane * 4 + t * 256;
        float4 v = *reinterpret_cast<const float4*>(rp + c);
        ss += v.x * v.x + v.y * v.y + v.z * v.z + v.w * v.w;
        ushort4 u;
        u.x = f2bf(v.x); u.y = f2bf(v.y); u.z = f2bf(v.z); u.w = f2bf(v.w);
        *reinterpret_cast<ushort4*>(wp + c) = u;
    }
#pragma unroll
    for (int off = 32; off; off >>= 1) ss += __shfl_xor(ss, off);
    if (lane == 0) nrm[row] = sqrtf(ss);
}

// ---------------------------------------------------------------------------
// Kernel 2: label histogram (integer LDS atomics -> deterministic).
// ---------------------------------------------------------------------------
__global__ __launch_bounds__(256) void hist_kernel(
    const int* __restrict__ labels, int* __restrict__ hist)
{
    __shared__ int h[128];
    int tid = threadIdx.x;
    if (tid < 128) h[tid] = 0;
    __syncthreads();
    for (int i = tid; i < NB; i += 256) atomicAdd(&h[labels[i]], 1);
    __syncthreads();
    if (tid < 128) hist[tid] = h[tid];
}

// ---------------------------------------------------------------------------
// Kernel 3: 256x128-tile bf16 GEMM, BK=32, 8x4 wave register tile.
// 4 waves: wr=wid&1 -> 128-row half, wc=wid>>1 -> 64-col half; each wave
// computes 128x64 = 32 MFMA/iter from 12 ds_read_b128 (375 B/MFMA, -27% LDS
// traffic per FLOP vs the 4x4 tile that plateaued at 24-27% MfmaUtil).
// Tri-buffered LDS (3 x 24 KiB = 72 KiB -> 2 blocks/CU). R8 pipeline:
// iter t stages tile t+2 (6 gloads), computes t, vmcnt(6) retires tile t+1
// (issued a full iteration earlier - never just-issued loads), lgkmcnt(0)
// [race fix: ds_reads drain before buffer handoff], s_barrier.
// Tail: t=30 vmcnt(0). 2048 blocks -> 8 rounds/CU (half of R8's 16).
// R8-verified swizzle (0 conflicts); XCD owns 4 tm rows (A 2MB L2-resident).
// Epilogue: scale to cos, write C, fused per-row loss partials.
// ---------------------------------------------------------------------------
__global__ __launch_bounds__(256, 2) void gemm_cos(
    const unsigned short* __restrict__ wa, const unsigned short* __restrict__ wb,
    const float* __restrict__ na, const float* __restrict__ nb,
    const int* __restrict__ labels,
    float* __restrict__ C, float* __restrict__ pe, float* __restrict__ pm)
{
    // 3 bufs x [A 256x32 (8192 sh) | B 128x32 (4096 sh)] = 36864 sh = 72 KiB
    __shared__ unsigned short lds[36864];

    const int bid = blockIdx.x;                 // 2048 blocks
    const int tm  = (bid & 7) * 4 + ((bid >> 3) & 3);   // 0..31, XCD-major
    const int tn  = bid >> 5;                            // 0..63, B streams

    const int tid  = threadIdx.x;
    const int lane = tid & 63;
    const int wid  = tid >> 6;
    const int wr   = wid & 1, wc = wid >> 1;
    const int l15  = lane & 15, lg = lane >> 4;

    const int m0 = tm * 256, n0 = tn * 128;

    // Staging: thread -> row tid>>2 (0..63 per gload), granule tid&3; global
    // granule pre-swizzled: (tid&3) ^ ((row>>1)&3)  [R8-verified].
    const int srow = tid >> 2;
    const int sg   = (tid & 3) ^ ((tid >> 3) & 3);
    const unsigned short* pA = wa + (size_t)(m0 + srow) * ND + sg * 8;
    const unsigned short* pB = wb + (size_t)(n0 + srow) * ND + sg * 8;
    const int stW = wid * 512;   // wave-uniform LDS dest base per 64-row call

    // Fragment reads: kg = (lg ^ ((row>>1)&3))*8; row bits from l15 only
    // (m*16 / n*16 / wr*128 / wc*64 do not disturb (row>>1)&3).
    const int kg  = (lg ^ ((lane >> 1) & 3)) * 8;
    const int rdA = wr * 4096 + l15 * 32 + kg;            // + m*512, m=0..7
    const int rdB = 8192 + (wc * 64 + l15) * 32 + kg;     // + n*512, n=0..3

    f32x4 acc[8][4];
#pragma unroll
    for (int i = 0; i < 8; ++i)
#pragma unroll
        for (int j = 0; j < 4; ++j) acc[i][j] = (f32x4){0.f, 0.f, 0.f, 0.f};

#define STAGE(t, BUF) do { \
    _Pragma("unroll") \
    for (int c_ = 0; c_ < 4; ++c_) \
        gload_lds16(pA + (size_t)c_ * 64 * ND + (t) * 32, \
                    &lds[(BUF) + c_ * 2048 + stW]); \
    _Pragma("unroll") \
    for (int c_ = 0; c_ < 2; ++c_) \
        gload_lds16(pB + (size_t)c_ * 64 * ND + (t) * 32, \
                    &lds[(BUF) + 8192 + c_ * 2048 + stW]); } while (0)

#define COMPUTE(BUF) do { \
    bf16x8 bq[4], af[4]; \
    _Pragma("unroll") \
    for (int n_ = 0; n_ < 4; ++n_) \
        bq[n_] = *reinterpret_cast<const bf16x8*>(&lds[(BUF) + rdB + n_ * 512]); \
    _Pragma("unroll") \
    for (int m_ = 0; m_ < 4; ++m_) \
        af[m_] = *reinterpret_cast<const bf16x8*>(&lds[(BUF) + rdA + m_ * 512]); \
    _Pragma("unroll") \
    for (int m_ = 0; m_ < 4; ++m_) \
        _Pragma("unroll") \
        for (int n_ = 0; n_ < 4; ++n_) \
            acc[m_][n_] = __builtin_amdgcn_mfma_f32_16x16x32_bf16( \
                af[m_], bq[n_], acc[m_][n_], 0, 0, 0); \
    _Pragma("unroll") \
    for (int m_ = 0; m_ < 4; ++m_) \
        af[m_] = *reinterpret_cast<const bf16x8*>(&lds[(BUF) + rdA + 2048 + m_ * 512]); \
    _Pragma("unroll") \
    for (int m_ = 0; m_ < 4; ++m_) \
        _Pragma("unroll") \
        for (int n_ = 0; n_ < 4; ++n_) \
            acc[4 + m_][n_] = __builtin_amdgcn_mfma_f32_16x16x32_bf16( \
                af[m_], bq[n_], acc[4 + m_][n_], 0, 0, 0); \
    } while (0)

    // Prologue: tiles 0,1 staged (12 loads/thread-set); wait tile 0 only.
    STAGE(0, 0);
    STAGE(1, 12288);
    VMCNT6();
    BARRIER();

#pragma unroll
    for (int t = 0; t < 32; ++t) {
        const int cb  = (t % 3) * 12288;
        const int nb2 = ((t + 2) % 3) * 12288;
        if (t < 30) STAGE(t + 2, nb2);        // issue-early (depth 2)
        COMPUTE(cb);                          // ~600+ cyc of load flight
        if (t < 30)      VMCNT6();            // retire tile t+1; keep t+2
        else if (t < 31) VMCNT0();            // drain tile 31
        LGKM0();                              // race fix: reads drained
        BARRIER();
    }

#undef COMPUTE
#undef STAGE

    // ---------------- epilogue: cos write + fused loss partials ------------
    __syncthreads();                 // LDS reusable
    float* pl = reinterpret_cast<float*>(lds);   // [256 rows][2 wc][2] floats

    float nbv[4]; int labc[4];
#pragma unroll
    for (int n = 0; n < 4; ++n) {
        int c = n0 + wc * 64 + n * 16 + l15;
        nbv[n] = nb[c]; labc[n] = labels[c];
    }

#pragma unroll
    for (int m = 0; m < 8; ++m) {
#pragma unroll
        for (int jj = 0; jj < 4; ++jj) {
            int rl = wr * 128 + m * 16 + lg * 4 + jj;   // 0..255
            int r  = m0 + rl;
            float nav = na[r]; int labr = labels[r];
            float es = 0.f, ms = 0.f;
#pragma unroll
            for (int n = 0; n < 4; ++n) {
                int c = n0 + wc * 64 + n * 16 + l15;
                float v = acc[m][n][jj] / fmaxf(nav * nbv[n], 1e-8f);
                C[(size_t)r * NB + c] = v;
                es += __expf(v);
                ms += (labc[n] == labr) ? v : 0.f;
            }
#pragma unroll
            for (int off = 1; off < 16; off <<= 1) {
                es += __shfl_xor(es, off);
                ms += __shfl_xor(ms, off);
            }
            if (l15 == 0) {
                int o = rl * 4 + wc * 2;
                pl[o] = es; pl[o + 1] = ms;
            }
        }
    }
    __syncthreads();
    if (tid < 256) {
        float es = pl[tid * 4]     + pl[tid * 4 + 2];
        float ms = pl[tid * 4 + 1] + pl[tid * 4 + 3];
        pe[tn * NB + m0 + tid] = es;
        pm[tn * NB + m0 + tid] = ms;
    }
}

// ---------------------------------------------------------------------------
// Kernel 4: reduce 64 column-tile partials -> per-row loss.
// ---------------------------------------------------------------------------
__global__ __launch_bounds__(256) void loss_final(
    const float* __restrict__ pe, const float* __restrict__ pm,
    const int* __restrict__ labels, const int* __restrict__ hist,
    float* __restrict__ per_row)
{
    int row = blockIdx.x * 256 + threadIdx.x;
    float es = 0.f, ms = 0.f;
#pragma unroll
    for (int t = 0; t < 64; ++t) {
        es += pe[t * NB + row];
        ms += pm[t * NB + row];
    }
    per_row[row] = logf(es) - ms / (float)hist[labels[row]];
}

// ---------------------------------------------------------------------------
// Kernel 5: deterministic mean of per_row -> out[0]
// ---------------------------------------------------------------------------
__global__ __launch_bounds__(256) void finalize(
    const float* __restrict__ per_row, float* __restrict__ out)
{
    __shared__ float sm[256];
    float s = 0.f;
    for (int i = threadIdx.x; i < NB; i += 256) s += per_row[i];
    sm[threadIdx.x] = s;
    __syncthreads();
    for (int k = 128; k; k >>= 1) {
        if (threadIdx.x < k) sm[threadIdx.x] += sm[threadIdx.x + k];
        __syncthreads();
    }
    if (threadIdx.x == 0) out[0] = sm[0] * (1.0f / (float)NB);
}

extern "C" void kernel_launch(void* const* d_in, const int* in_sizes, int n_in,
                              void* d_out, int out_size, void* d_ws, size_t ws_size,
                              hipStream_t stream) {
    const int*   labels = (const int*)d_in[0];
    const float* A      = (const float*)d_in[1];
    const float* Bm     = (const float*)d_in[2];
    float* out = (float*)d_out;

    // workspace layout (~38.2 MB)
    char* ws = (char*)d_ws;
    unsigned short* wa = (unsigned short*)(ws);                     // 16 MB
    unsigned short* wb = (unsigned short*)(ws + 16777216);          // 16 MB
    float* na      = (float*)(ws + 33554432);                       // 32 KB
    float* nb      = (float*)(ws + 33554432 + 32768);               // 32 KB
    float* per_row = (float*)(ws + 33554432 + 65536);               // 32 KB
    int*   hist    = (int*)  (ws + 33554432 + 98304);               // 512 B
    float* pe      = (float*)(ws + 33554432 + 131072);              // 2 MB
    float* pm      = (float*)(ws + 33554432 + 131072 + 2097152);    // 2 MB

    float* cosm = out + 1;   // out[0]=loss, out[1..] = cos_score row-major

    prep_kernel<<<4096, 256, 0, stream>>>(A, Bm, wa, wb, na, nb);
    hist_kernel<<<1,    256, 0, stream>>>(labels, hist);
    gemm_cos   <<<2048, 256, 0, stream>>>(wa, wb, na, nb, labels, cosm, pe, pm);
    loss_final <<<32,   256, 0, stream>>>(pe, pm, labels, hist, per_row);
    finalize   <<<1,    256, 0, stream>>>(per_row, out);
}